// Round 2
// baseline (129.633 us; speedup 1.0000x reference)
//
#include <hip/hip_runtime.h>

// LengthRegulator: B=16, T=512, D=384, MAX_LEN=4096
// out[b,f,:] = x[b, searchsorted_right(cum[b], f).clip(0,T-1), :] * (f < min(mel,max_len))
// mel_len[b] = sum(durations[b])  (written as f32 at the tail of d_out)

#define B_ 16
#define T_ 512
#define D_ 384
#define MAXLEN_ 4096
#define ROWV4_ (D_ / 4)                 // 96 float4 per row
#define OUT_ELEMS_ (B_ * MAXLEN_ * D_) // 25,165,824

#define FPB_ 64                         // frames per gather block
#define GT_ 384                         // gather block threads = 4 frames x 96 cols per sweep
#define BPB_ (MAXLEN_ / FPB_)           // 64 blocks per batch

typedef float vf4 __attribute__((ext_vector_type(4))); // native vector: nontemporal-store-able

// Kernel 1: per-batch inclusive cumsum -> ws (B*T ints); mel_len -> d_out tail.
// Shuffle-based scan: 6 shfl steps per wave + 8-wide wave-sum scan, 2 barriers.
__global__ __launch_bounds__(T_) void lr_scan_kernel(const int* __restrict__ dur,
                                                     int* __restrict__ cum_ws,
                                                     float* __restrict__ mel_out) {
    const int b = blockIdx.x, t = threadIdx.x;
    const int lane = t & 63, w = t >> 6;
    int v = dur[b * T_ + t];
    #pragma unroll
    for (int off = 1; off < 64; off <<= 1) {
        int n = __shfl_up(v, off);
        if (lane >= off) v += n;
    }
    __shared__ int wsum[8];
    if (lane == 63) wsum[w] = v;
    __syncthreads();
    if (t < 8) { // scan the 8 wave totals
        int u = wsum[t];
        #pragma unroll
        for (int off = 1; off < 8; off <<= 1) {
            int n = __shfl_up(u, off);
            if (t >= off) u += n;
        }
        wsum[t] = u;
    }
    __syncthreads();
    const int cum = v + (w > 0 ? wsum[w - 1] : 0);
    cum_ws[b * T_ + t] = cum;
    if (t == T_ - 1) mel_out[b] = (float)cum;
}

// Kernel 2: one block = 64 consecutive frames of one batch.
//   phase 1: stage cum[512] once (int4 loads)
//   phase 2: 64 threads -> 64 binary searches -> sidx[] (amortized 96x vs 1-per-float4)
//   phase 3: 384 threads sweep 4 frames x 96 cols; 16 float4 copies/thread,
//            nontemporal stores (streaming writes, keep x resident in L2)
__global__ __launch_bounds__(GT_) void lr_gather_kernel(const vf4* __restrict__ x,
                                                        const int* __restrict__ cum_ws,
                                                        const int* __restrict__ max_len_p,
                                                        vf4* __restrict__ out) {
    __shared__ int s[T_];
    __shared__ int sidx[FPB_];
    const int t = threadIdx.x;
    const int b = blockIdx.x / BPB_;
    const int f0 = (blockIdx.x - b * BPB_) * FPB_;

    if (t < T_ / 4)
        ((int4*)s)[t] = ((const int4*)(cum_ws + b * T_))[t];
    __syncthreads();

    if (t < FPB_) {
        const int f = f0 + t;
        const int lim = min(s[T_ - 1], max_len_p[0]);
        int idx = -1;                   // -1 => invalid frame, write zeros
        if (f < lim) {
            // searchsorted(cum, f, 'right') = #{i : cum[i] <= f}; 9-step branchless
            idx = 0;
            #pragma unroll
            for (int step = 256; step > 0; step >>= 1)
                if (s[idx + step - 1] <= f) idx += step;
            if (idx > T_ - 1) idx = T_ - 1; // clip (unreachable given f < mel, safety)
        }
        sidx[t] = idx;
    }
    __syncthreads();

    const int fl = t / 96;              // frame-in-sweep 0..3 (one magic-mul, once)
    const int col = t - fl * 96;        // float4 column 0..95
    const vf4* xb = x + (size_t)(b * T_) * ROWV4_;
    vf4* ob = out + ((size_t)b * MAXLEN_ + f0) * ROWV4_;
    const vf4 zero = (vf4)(0.f);

    #pragma unroll
    for (int k = 0; k < FPB_ / 4; ++k) { // 16 iterations, fully unrolled
        const int f = fl + 4 * k;
        const int idx = sidx[f];        // wave-uniform (<=2 frames per wave) -> broadcast
        vf4 v = zero;
        if (idx >= 0) v = xb[idx * ROWV4_ + col];
        __builtin_nontemporal_store(v, &ob[f * ROWV4_ + col]);
    }
}

extern "C" void kernel_launch(void* const* d_in, const int* in_sizes, int n_in,
                              void* d_out, int out_size, void* d_ws, size_t ws_size,
                              hipStream_t stream) {
    const float* x = (const float*)d_in[0];
    const int* dur = (const int*)d_in[1];
    const int* max_len_p = (const int*)d_in[2]; // device scalar — read in-kernel only

    float* out = (float*)d_out;
    float* mel_out = out + OUT_ELEMS_;
    int* cum_ws = (int*)d_ws; // B*T ints = 32 KB scratch

    lr_scan_kernel<<<B_, T_, 0, stream>>>(dur, cum_ws, mel_out);

    lr_gather_kernel<<<B_ * BPB_, GT_, 0, stream>>>(
        (const vf4*)x, cum_ws, max_len_p, (vf4*)out);
}

// Round 3
// 122.096 us; speedup vs baseline: 1.0617x; 1.0617x over previous
//
#include <hip/hip_runtime.h>

// LengthRegulator: B=16, T=512, D=384, MAX_LEN=4096
// out[b,f,:] = x[b, searchsorted_right(cum[b], f).clip(0,T-1), :] * (f < min(mel,max_len))
// mel_len[b] = sum(durations[b])  (written as f32 at the tail of d_out)

#define B_ 16
#define T_ 512
#define D_ 384
#define MAXLEN_ 4096
#define ROWV4_ (D_ / 4)                 // 96 float4 per row
#define OUT_ELEMS_ (B_ * MAXLEN_ * D_) // 25,165,824

#define FPB_ 64                         // frames per gather block
#define GT_ 384                         // gather block threads = 4 frames x 96 cols per sweep
#define BPB_ (MAXLEN_ / FPB_)           // 64 blocks per batch
#define KK_ (FPB_ / 4)                  // 16 frames per thread-sweep

typedef float vf4 __attribute__((ext_vector_type(4)));

// Kernel 1: per-batch inclusive cumsum -> ws (B*T ints); mel_len -> d_out tail.
__global__ __launch_bounds__(T_) void lr_scan_kernel(const int* __restrict__ dur,
                                                     int* __restrict__ cum_ws,
                                                     float* __restrict__ mel_out) {
    const int b = blockIdx.x, t = threadIdx.x;
    const int lane = t & 63, w = t >> 6;
    int v = dur[b * T_ + t];
    #pragma unroll
    for (int off = 1; off < 64; off <<= 1) {
        int n = __shfl_up(v, off);
        if (lane >= off) v += n;
    }
    __shared__ int wsum[8];
    if (lane == 63) wsum[w] = v;
    __syncthreads();
    if (t < 8) {
        int u = wsum[t];
        #pragma unroll
        for (int off = 1; off < 8; off <<= 1) {
            int n = __shfl_up(u, off);
            if (t >= off) u += n;
        }
        wsum[t] = u;
    }
    __syncthreads();
    const int cum = v + (w > 0 ? wsum[w - 1] : 0);
    cum_ws[b * T_ + t] = cum;
    if (t == T_ - 1) mel_out[b] = (float)cum;
}

// Kernel 2: one block = 64 consecutive frames of one batch. Three block-uniform paths:
//   zero path  (f0 >= lim):        no LDS, no barriers — 16 back-to-back zero stores (fill-like)
//   valid path (f0+64 <= lim):     stage cum + 64 searches, then 16 loads -> 16 stores
//                                  register-pipelined (stores never queue behind loads)
//   boundary   (16 blocks total):  masked variant of valid path
__global__ __launch_bounds__(GT_) void lr_gather_kernel(const vf4* __restrict__ x,
                                                        const int* __restrict__ cum_ws,
                                                        const int* __restrict__ max_len_p,
                                                        vf4* __restrict__ out) {
    __shared__ int s[T_];
    __shared__ int sidx[FPB_];
    const int t = threadIdx.x;
    const int b = blockIdx.x / BPB_;
    const int f0 = (blockIdx.x - b * BPB_) * FPB_;

    const int lim = min(cum_ws[b * T_ + T_ - 1], max_len_p[0]); // block-uniform scalar

    const int fl = t / 96;              // frame-in-sweep 0..3
    const int col = t - fl * 96;        // float4 column 0..95
    vf4* ob = out + ((size_t)b * MAXLEN_ + f0) * ROWV4_;

    if (f0 >= lim) {                    // -------- pure zero stream (no LDS, no barriers)
        const vf4 zero = (vf4)(0.f);
        #pragma unroll
        for (int k = 0; k < KK_; ++k)
            ob[(fl + 4 * k) * ROWV4_ + col] = zero;
        return;
    }

    // stage this batch's cum (128 int4 loads) and do the 64 searches once per block
    if (t < T_ / 4)
        ((int4*)s)[t] = ((const int4*)(cum_ws + b * T_))[t];
    __syncthreads();

    if (t < FPB_) {
        const int f = f0 + t;
        int idx = -1;                   // -1 => invalid frame (only in boundary blocks)
        if (f < lim) {
            // searchsorted(cum, f, 'right') = #{i : cum[i] <= f}; 9-step branchless
            idx = 0;
            #pragma unroll
            for (int step = 256; step > 0; step >>= 1)
                if (s[idx + step - 1] <= f) idx += step;
            if (idx > T_ - 1) idx = T_ - 1;
        }
        sidx[t] = idx;
    }
    __syncthreads();

    const vf4* xb = x + (size_t)(b * T_) * ROWV4_;

    // pull the 16 indices into registers (LDS broadcast reads)
    int idxr[KK_];
    #pragma unroll
    for (int k = 0; k < KK_; ++k)
        idxr[k] = sidx[fl + 4 * k];

    if (f0 + FPB_ <= lim) {             // -------- fully valid: unmasked pipeline
        vf4 v[KK_];
        #pragma unroll
        for (int k = 0; k < KK_; ++k)
            v[k] = xb[idxr[k] * ROWV4_ + col];
        #pragma unroll
        for (int k = 0; k < KK_; ++k)
            ob[(fl + 4 * k) * ROWV4_ + col] = v[k];
    } else {                            // -------- boundary block (1 per batch): masked
        const vf4 zero = (vf4)(0.f);
        vf4 v[KK_];
        #pragma unroll
        for (int k = 0; k < KK_; ++k) {
            v[k] = zero;
            if (idxr[k] >= 0) v[k] = xb[idxr[k] * ROWV4_ + col];
        }
        #pragma unroll
        for (int k = 0; k < KK_; ++k)
            ob[(fl + 4 * k) * ROWV4_ + col] = v[k];
    }
}

extern "C" void kernel_launch(void* const* d_in, const int* in_sizes, int n_in,
                              void* d_out, int out_size, void* d_ws, size_t ws_size,
                              hipStream_t stream) {
    const float* x = (const float*)d_in[0];
    const int* dur = (const int*)d_in[1];
    const int* max_len_p = (const int*)d_in[2]; // device scalar — read in-kernel only

    float* out = (float*)d_out;
    float* mel_out = out + OUT_ELEMS_;
    int* cum_ws = (int*)d_ws; // B*T ints = 32 KB scratch

    lr_scan_kernel<<<B_, T_, 0, stream>>>(dur, cum_ws, mel_out);

    lr_gather_kernel<<<B_ * BPB_, GT_, 0, stream>>>(
        (const vf4*)x, cum_ws, max_len_p, (vf4*)out);
}